// Round 1
// baseline (342.840 us; speedup 1.0000x reference)
//
#include <hip/hip_runtime.h>
#include <hip/hip_bf16.h>

typedef __attribute__((ext_vector_type(8))) short bf16x8;
typedef __attribute__((ext_vector_type(4))) float f32x4;

__device__ __forceinline__ unsigned short f2bf(float f) {
  union { float f; unsigned int u; } a; a.f = f;
  unsigned int u = a.u;
  u += 0x7FFFu + ((u >> 16) & 1u);   // RNE
  return (unsigned short)(u >> 16);
}

#define TM 128
#define TN 128
#define TK 32
#define LK 40   // LDS row stride (elems): 32 + 8 pad -> 80B rows, 16B aligned, 2-way bank alias (free)

// C = A[M][K] * B[N][K]^T, bf16 inputs, fp32 accum.
// MODE 0: store bf16 C[M][N]
// MODE 1: store bf16 transposed per-batch: Vt[b][n][s], s = row % 2048 (rows span batches)
// MODE 2: scores: store fp32 C[M][N] * scale, skip blocks fully above diagonal
// MODE 3: PV: store fp32 C[M][N]; K-loop clamped to bm+TM (P zero above diagonal)
template<int MODE>
__global__ __launch_bounds__(256)
void gemm_bt(const unsigned short* __restrict__ A,
             const unsigned short* __restrict__ Bm,
             float* __restrict__ Cf,
             unsigned short* __restrict__ Cb,
             int M, int N, int K,
             long aBatch, long bBatch, long cBatch,
             float scale)
{
  int z = blockIdx.z;
  A  += (long)z * aBatch;
  Bm += (long)z * bBatch;
  if (MODE == 2 || MODE == 3) Cf += (long)z * cBatch;

  int bm = blockIdx.y * TM;
  int bn = blockIdx.x * TN;
  if (MODE == 2 && bn > bm + (TM - 1)) return;   // fully above causal diagonal
  int Keff = K;
  if (MODE == 3) Keff = min(K, bm + TM);

  __shared__ __align__(16) unsigned short As[TM * LK];
  __shared__ __align__(16) unsigned short Bs[TN * LK];

  int tid  = threadIdx.x;
  int wave = tid >> 6, lane = tid & 63;
  int wm = (wave >> 1) * 64, wn = (wave & 1) * 64;
  int quad = lane >> 4, l16 = lane & 15;
  int srow = tid >> 2, sch = tid & 3;   // staging: 4 chunks of 16B per 64B row

  f32x4 acc[4][4] = {};

  const long rowA0 = (long)(bm + srow) * K + sch * 8;
  const long rowA1 = rowA0 + (long)64 * K;
  const long rowB0 = (long)(bn + srow) * K + sch * 8;
  const long rowB1 = rowB0 + (long)64 * K;

  for (int k0 = 0; k0 < Keff; k0 += TK) {
    int4 a0 = *(const int4*)(A  + rowA0 + k0);
    int4 a1 = *(const int4*)(A  + rowA1 + k0);
    int4 b0 = *(const int4*)(Bm + rowB0 + k0);
    int4 b1 = *(const int4*)(Bm + rowB1 + k0);
    *(int4*)&As[srow * LK + sch * 8]        = a0;
    *(int4*)&As[(srow + 64) * LK + sch * 8] = a1;
    *(int4*)&Bs[srow * LK + sch * 8]        = b0;
    *(int4*)&Bs[(srow + 64) * LK + sch * 8] = b1;
    __syncthreads();

    bf16x8 af[4], bfr[4];
#pragma unroll
    for (int i = 0; i < 4; i++)
      af[i] = *(const bf16x8*)&As[(wm + i * 16 + l16) * LK + quad * 8];
#pragma unroll
    for (int j = 0; j < 4; j++)
      bfr[j] = *(const bf16x8*)&Bs[(wn + j * 16 + l16) * LK + quad * 8];
#pragma unroll
    for (int i = 0; i < 4; i++)
#pragma unroll
      for (int j = 0; j < 4; j++)
        acc[i][j] = __builtin_amdgcn_mfma_f32_16x16x32_bf16(af[i], bfr[j], acc[i][j], 0, 0, 0);
    __syncthreads();
  }

  // Epilogue. C/D layout: col = lane&15, row = quad*4 + reg  [measured m89/m91]
#pragma unroll
  for (int i = 0; i < 4; i++) {
    int grow0 = bm + wm + i * 16 + quad * 4;
#pragma unroll
    for (int j = 0; j < 4; j++) {
      int gcol = bn + wn + j * 16 + l16;
      if (MODE == 0) {
#pragma unroll
        for (int r = 0; r < 4; r++)
          Cb[(long)(grow0 + r) * N + gcol] = f2bf(acc[i][j][r]);
      } else if (MODE == 1) {
        int bb = grow0 >> 11, s = grow0 & 2047;   // batch, seq (4-row group never crosses batch)
        ushort4 pk;
        pk.x = f2bf(acc[i][j][0]); pk.y = f2bf(acc[i][j][1]);
        pk.z = f2bf(acc[i][j][2]); pk.w = f2bf(acc[i][j][3]);
        *(ushort4*)(Cb + ((long)bb * 1024 + gcol) * 2048 + s) = pk;
      } else if (MODE == 2) {
#pragma unroll
        for (int r = 0; r < 4; r++)
          Cf[(long)(grow0 + r) * N + gcol] = acc[i][j][r] * scale;
      } else {
#pragma unroll
        for (int r = 0; r < 4; r++)
          Cf[(long)(grow0 + r) * N + gcol] = acc[i][j][r];
      }
    }
  }
}

__global__ __launch_bounds__(256)
void cvt_bf16(const float* __restrict__ in, unsigned short* __restrict__ out, long n)
{
  long i = ((long)blockIdx.x * 256 + threadIdx.x) * 4;
  if (i >= n) return;
  float4 v = *(const float4*)(in + i);
  ushort4 o;
  o.x = f2bf(v.x); o.y = f2bf(v.y); o.z = f2bf(v.z); o.w = f2bf(v.w);
  *(ushort4*)(out + i) = o;
}

// W[k][n] fp32 -> WT[n][k] bf16 (1024x1024), 3 matrices via blockIdx.z
__global__ __launch_bounds__(256)
void trans_cvt(const float* __restrict__ W0, const float* __restrict__ W1, const float* __restrict__ W2,
               unsigned short* __restrict__ T0, unsigned short* __restrict__ T1, unsigned short* __restrict__ T2)
{
  int z = blockIdx.z;
  const float* W   = (z == 0) ? W0 : (z == 1) ? W1 : W2;
  unsigned short* T = (z == 0) ? T0 : (z == 1) ? T1 : T2;
  __shared__ float tile[32][33];
  int kb = blockIdx.x * 32, nb = blockIdx.y * 32;
  int tx = threadIdx.x & 31, ty = threadIdx.x >> 5;
  for (int r = ty; r < 32; r += 8)
    tile[r][tx] = W[(long)(kb + r) * 1024 + nb + tx];
  __syncthreads();
  for (int r = ty; r < 32; r += 8)
    T[(long)(nb + r) * 1024 + kb + tx] = f2bf(tile[tx][r]);
}

// one 256-thread block per row; reads S[row][0..row], writes P bf16 (zeros above diag)
__global__ __launch_bounds__(256)
void softmax_rows(const float* __restrict__ Sc, unsigned short* __restrict__ P)
{
  int row = blockIdx.x, b = blockIdx.y;
  const float* Sr = Sc + ((long)b * 2048 + row) * 2048;
  unsigned short* Pr = P + ((long)b * 2048 + row) * 2048;
  int n = row + 1;
  int tid = threadIdx.x;
  int wave = tid >> 6, lane = tid & 63;
  __shared__ float sh[2048];
  __shared__ float red[4];

  float lmax = -1e30f;
  for (int j = tid; j < n; j += 256) { float v = Sr[j]; sh[j] = v; lmax = fmaxf(lmax, v); }
  for (int off = 32; off; off >>= 1) lmax = fmaxf(lmax, __shfl_down(lmax, off));
  if (lane == 0) red[wave] = lmax;
  __syncthreads();
  float rmax = fmaxf(fmaxf(red[0], red[1]), fmaxf(red[2], red[3]));
  __syncthreads();

  float lsum = 0.f;
  for (int j = tid; j < n; j += 256) { float e = __expf(sh[j] - rmax); sh[j] = e; lsum += e; }
  for (int off = 32; off; off >>= 1) lsum += __shfl_down(lsum, off);
  if (lane == 0) red[wave] = lsum;
  __syncthreads();
  float rinv = 1.0f / (red[0] + red[1] + red[2] + red[3]);

  for (int j = tid; j < 2048; j += 256)
    Pr[j] = (j < n) ? f2bf(sh[j] * rinv) : (unsigned short)0;
}

extern "C" void kernel_launch(void* const* d_in, const int* in_sizes, int n_in,
                              void* d_out, int out_size, void* d_ws, size_t ws_size,
                              hipStream_t stream) {
  const float* x  = (const float*)d_in[0];
  const float* Wq = (const float*)d_in[1];
  const float* Wk = (const float*)d_in[2];
  const float* Wv = (const float*)d_in[3];
  float* out = (float*)d_out;

  // workspace layout (bf16 = unsigned short), ~166 MB total
  unsigned short* Xb  = (unsigned short*)d_ws;            // [8192][1024]
  unsigned short* WqT = Xb  + (long)8192 * 1024;          // [1024][1024] (n-major)
  unsigned short* WkT = WqT + (long)1024 * 1024;
  unsigned short* WvT = WkT + (long)1024 * 1024;
  unsigned short* Q   = WvT + (long)1024 * 1024;          // [8192][1024]
  unsigned short* Kb  = Q   + (long)8192 * 1024;          // [8192][1024]
  unsigned short* Vt  = Kb  + (long)8192 * 1024;          // [4][1024][2048]
  float* Sc           = (float*)(Vt + (long)8192 * 1024); // [4][2048][2048] fp32
  unsigned short* P   = (unsigned short*)(Sc + (long)4 * 2048 * 2048); // [4][2048][2048]

  cvt_bf16<<<8192, 256, 0, stream>>>(x, Xb, (long)8388608);
  trans_cvt<<<dim3(32, 32, 3), 256, 0, stream>>>(Wq, Wk, Wv, WqT, WkT, WvT);

  // projections: [8192x1024] = Xb * W^T
  gemm_bt<0><<<dim3(8, 64, 1), 256, 0, stream>>>(Xb, WqT, nullptr, Q,  8192, 1024, 1024, 0, 0, 0, 1.f);
  gemm_bt<0><<<dim3(8, 64, 1), 256, 0, stream>>>(Xb, WkT, nullptr, Kb, 8192, 1024, 1024, 0, 0, 0, 1.f);
  gemm_bt<1><<<dim3(8, 64, 1), 256, 0, stream>>>(Xb, WvT, nullptr, Vt, 8192, 1024, 1024, 0, 0, 0, 1.f);

  // scores: per batch [2048x2048] = Q * K^T / 32, lower-triangle blocks only
  gemm_bt<2><<<dim3(16, 16, 4), 256, 0, stream>>>(Q, Kb, Sc, nullptr, 2048, 2048, 1024,
      (long)2048 * 1024, (long)2048 * 1024, (long)2048 * 2048, 0.03125f);

  softmax_rows<<<dim3(2048, 4), 256, 0, stream>>>(Sc, P);

  // out: per batch [2048x1024] = P * Vt^T, K clamped per block-row
  gemm_bt<3><<<dim3(8, 16, 4), 256, 0, stream>>>(P, Vt, out, nullptr, 2048, 1024, 2048,
      (long)2048 * 2048, (long)1024 * 2048, (long)2048 * 1024, 1.f);
}

// Round 2
// 298.144 us; speedup vs baseline: 1.1499x; 1.1499x over previous
//
#include <hip/hip_runtime.h>

typedef __attribute__((ext_vector_type(8))) short bf16x8;
typedef __attribute__((ext_vector_type(4))) float f32x4;
typedef unsigned int u32;

__device__ __forceinline__ unsigned short f2bf(float f) {
  union { float f; unsigned int u; } a; a.f = f;
  unsigned int u = a.u;
  u += 0x7FFFu + ((u >> 16) & 1u);   // RNE
  return (unsigned short)(u >> 16);
}

// async global->LDS, 16B per lane. LDS dest = wave-uniform base + lane*16.
__device__ __forceinline__ void gload16(const unsigned short* g, unsigned short* l) {
  __builtin_amdgcn_global_load_lds((const __attribute__((address_space(1))) u32*)g,
                                   (__attribute__((address_space(3))) u32*)l, 16, 0, 0);
}

#define TM 128
#define TN 128
#define TK 32
// LDS tile: [128 rows][32 elems] = 64B/row, no padding (required by global_load_lds).
// Bank conflicts broken by XOR chunk swizzle: 16B chunk p holds logical chunk
// p ^ ((row>>1)&3). Write side: swizzle folded into per-lane GLOBAL address.
// Read side: pc = quad ^ ((l16>>1)&3)  (row-base multiples of 16 drop out).

// C = A[M][K] * B[N][K]^T, bf16 in, fp32 accum.
// MODE 0: fused QKV. B = Wcat[3072][1024]; n-range 0->Q bf16, 1->K bf16, 2->Vt transposed
// MODE 2: scores: fp32 C*scale, stride 2048, skip blocks above diagonal
// MODE 3: PV: fp32 C, stride 1024, K clamped to bm+TM
template<int MODE>
__global__ __launch_bounds__(256)
void gemm_bt(const unsigned short* __restrict__ A,
             const unsigned short* __restrict__ Bm,
             float* __restrict__ Cf,
             unsigned short* __restrict__ Cb,
             int K, long aBatch, long bBatch, long cBatch, float scale)
{
  int z = blockIdx.z;
  A  += (long)z * aBatch;
  Bm += (long)z * bBatch;
  if (MODE == 2 || MODE == 3) Cf += (long)z * cBatch;

  int bm = blockIdx.y * TM;
  int bn = blockIdx.x * TN;
  if (MODE == 2 && bn > bm + (TM - 1)) return;   // fully above causal diagonal
  int Keff = K;
  if (MODE == 3) Keff = min(K, bm + TM);

  __shared__ __align__(16) unsigned short As[TM * TK];
  __shared__ __align__(16) unsigned short Bs[TN * TK];

  int tid  = threadIdx.x;
  int wave = tid >> 6, lane = tid & 63;
  int wm = (wave >> 1) * 64, wn = (wave & 1) * 64;
  int quad = lane >> 4, l16 = lane & 15;

  // ---- staging coords: wave stages rows [wave*32, wave*32+32) of As and Bs,
  // two 16-row instructions each. lane -> row rs, chunk p; global chunk c swizzled.
  int rs = wave * 32 + (lane >> 2);
  int p  = lane & 3;
  int c  = p ^ ((rs >> 1) & 3);           // same for rs and rs+16 (16>>1=8, 8&3=0)
  const unsigned short* Ag0 = A  + (long)(bm + rs) * K + c * 8;
  const unsigned short* Ag1 = Ag0 + (long)16 * K;
  const unsigned short* Bg0 = Bm + (long)(bn + rs) * K + c * 8;
  const unsigned short* Bg1 = Bg0 + (long)16 * K;
  unsigned short* Al0 = &As[(wave * 32) * TK];
  unsigned short* Al1 = &As[(wave * 32 + 16) * TK];
  unsigned short* Bl0 = &Bs[(wave * 32) * TK];
  unsigned short* Bl1 = &Bs[(wave * 32 + 16) * TK];

  // ---- fragment read swizzle (block-row-base independent)
  int pc = quad ^ ((l16 >> 1) & 3);
  int fragOffA[4], fragOffB[4];
#pragma unroll
  for (int i = 0; i < 4; i++) {
    fragOffA[i] = (wm + i * 16 + l16) * TK + pc * 8;
    fragOffB[i] = (wn + i * 16 + l16) * TK + pc * 8;
  }

  f32x4 acc[4][4] = {};

  for (int k0 = 0; k0 < Keff; k0 += TK) {
    gload16(Ag0 + k0, Al0);
    gload16(Ag1 + k0, Al1);
    gload16(Bg0 + k0, Bl0);
    gload16(Bg1 + k0, Bl1);
    __syncthreads();   // compiler emits vmcnt(0) drain before barrier

    bf16x8 af[4], bfr[4];
#pragma unroll
    for (int i = 0; i < 4; i++) af[i]  = *(const bf16x8*)&As[fragOffA[i]];
#pragma unroll
    for (int j = 0; j < 4; j++) bfr[j] = *(const bf16x8*)&Bs[fragOffB[j]];
#pragma unroll
    for (int i = 0; i < 4; i++)
#pragma unroll
      for (int j = 0; j < 4; j++)
        acc[i][j] = __builtin_amdgcn_mfma_f32_16x16x32_bf16(af[i], bfr[j], acc[i][j], 0, 0, 0);
    __syncthreads();
  }

  // Epilogue. C/D layout: col = lane&15, row = quad*4 + reg  [m89/m91]
#pragma unroll
  for (int i = 0; i < 4; i++) {
    int grow0 = bm + wm + i * 16 + quad * 4;
#pragma unroll
    for (int j = 0; j < 4; j++) {
      int gcol = bn + wn + j * 16 + l16;
      if (MODE == 0) {
        int which = gcol >> 10;       // block-uniform (bn multiple of 128)
        int col = gcol & 1023;
        if (which < 2) {
          unsigned short* dst = Cb + (long)which * 8192 * 1024;   // Q or K
#pragma unroll
          for (int r = 0; r < 4; r++)
            dst[(long)(grow0 + r) * 1024 + col] = f2bf(acc[i][j][r]);
        } else {                       // Vt[b][col][s], 4-row pack along s
          unsigned short* Vt = Cb + (long)2 * 8192 * 1024;
          int bb = grow0 >> 11, s = grow0 & 2047;
          ushort4 pk;
          pk.x = f2bf(acc[i][j][0]); pk.y = f2bf(acc[i][j][1]);
          pk.z = f2bf(acc[i][j][2]); pk.w = f2bf(acc[i][j][3]);
          *(ushort4*)(Vt + ((long)bb * 1024 + col) * 2048 + s) = pk;
        }
      } else if (MODE == 2) {
#pragma unroll
        for (int r = 0; r < 4; r++)
          Cf[(long)(grow0 + r) * 2048 + gcol] = acc[i][j][r] * scale;
      } else {
#pragma unroll
        for (int r = 0; r < 4; r++)
          Cf[(long)(grow0 + r) * 1024 + gcol] = acc[i][j][r];
      }
    }
  }
}

__global__ __launch_bounds__(256)
void cvt_bf16(const float* __restrict__ in, unsigned short* __restrict__ out, long n)
{
  long i = ((long)blockIdx.x * 256 + threadIdx.x) * 4;
  if (i >= n) return;
  float4 v = *(const float4*)(in + i);
  ushort4 o;
  o.x = f2bf(v.x); o.y = f2bf(v.y); o.z = f2bf(v.z); o.w = f2bf(v.w);
  *(ushort4*)(out + i) = o;
}

// W[k][n] fp32 -> WT[n][k] bf16 (1024x1024), 3 matrices via blockIdx.z
__global__ __launch_bounds__(256)
void trans_cvt(const float* __restrict__ W0, const float* __restrict__ W1, const float* __restrict__ W2,
               unsigned short* __restrict__ T0, unsigned short* __restrict__ T1, unsigned short* __restrict__ T2)
{
  int z = blockIdx.z;
  const float* W   = (z == 0) ? W0 : (z == 1) ? W1 : W2;
  unsigned short* T = (z == 0) ? T0 : (z == 1) ? T1 : T2;
  __shared__ float tile[32][33];
  int kb = blockIdx.x * 32, nb = blockIdx.y * 32;
  int tx = threadIdx.x & 31, ty = threadIdx.x >> 5;
  for (int r = ty; r < 32; r += 8)
    tile[r][tx] = W[(long)(kb + r) * 1024 + nb + tx];
  __syncthreads();
  for (int r = ty; r < 32; r += 8)
    T[(long)(nb + r) * 1024 + kb + tx] = f2bf(tile[tx][r]);
}

// one 256-thread block per row; reads S[row][0..row], writes P bf16 (zeros above diag)
__global__ __launch_bounds__(256)
void softmax_rows(const float* __restrict__ Sc, unsigned short* __restrict__ P)
{
  int row = blockIdx.x, b = blockIdx.y;
  const float* Sr = Sc + ((long)b * 2048 + row) * 2048;
  unsigned short* Pr = P + ((long)b * 2048 + row) * 2048;
  int n = row + 1;
  int tid = threadIdx.x;
  int wave = tid >> 6, lane = tid & 63;
  __shared__ float sh[2048];
  __shared__ float red[4];

  float lmax = -1e30f;
  for (int j = tid; j < n; j += 256) { float v = Sr[j]; sh[j] = v; lmax = fmaxf(lmax, v); }
  for (int off = 32; off; off >>= 1) lmax = fmaxf(lmax, __shfl_down(lmax, off));
  if (lane == 0) red[wave] = lmax;
  __syncthreads();
  float rmax = fmaxf(fmaxf(red[0], red[1]), fmaxf(red[2], red[3]));
  __syncthreads();

  float lsum = 0.f;
  for (int j = tid; j < n; j += 256) { float e = __expf(sh[j] - rmax); sh[j] = e; lsum += e; }
  for (int off = 32; off; off >>= 1) lsum += __shfl_down(lsum, off);
  if (lane == 0) red[wave] = lsum;
  __syncthreads();
  float rinv = 1.0f / (red[0] + red[1] + red[2] + red[3]);

  for (int j = tid; j < 2048; j += 256)
    Pr[j] = (j < n) ? f2bf(sh[j] * rinv) : (unsigned short)0;
}

extern "C" void kernel_launch(void* const* d_in, const int* in_sizes, int n_in,
                              void* d_out, int out_size, void* d_ws, size_t ws_size,
                              hipStream_t stream) {
  const float* x  = (const float*)d_in[0];
  const float* Wq = (const float*)d_in[1];
  const float* Wk = (const float*)d_in[2];
  const float* Wv = (const float*)d_in[3];
  float* out = (float*)d_out;

  // workspace layout (bf16 = unsigned short), ~166 MB total
  unsigned short* Xb  = (unsigned short*)d_ws;            // [8192][1024]
  unsigned short* WqT = Xb  + (long)8192 * 1024;          // [3072][1024] contiguous (q,k,v)
  unsigned short* WkT = WqT + (long)1024 * 1024;
  unsigned short* WvT = WkT + (long)1024 * 1024;
  unsigned short* Q   = WvT + (long)1024 * 1024;          // [8192][1024]
  unsigned short* Kb  = Q   + (long)8192 * 1024;          // [8192][1024]
  unsigned short* Vt  = Kb  + (long)8192 * 1024;          // [4][1024][2048]
  float* Sc           = (float*)(Vt + (long)8192 * 1024); // [4][2048][2048] fp32
  unsigned short* P   = (unsigned short*)(Sc + (long)4 * 2048 * 2048); // [4][2048][2048]

  cvt_bf16<<<8192, 256, 0, stream>>>(x, Xb, (long)8388608);
  trans_cvt<<<dim3(32, 32, 3), 256, 0, stream>>>(Wq, Wk, Wv, WqT, WkT, WvT);

  // fused QKV: [8192x3072] = Xb * Wcat^T, epilogue splits into Q, K, Vt
  gemm_bt<0><<<dim3(24, 64, 1), 256, 0, stream>>>(Xb, WqT, nullptr, Q, 1024, 0, 0, 0, 1.f);

  // scores: per batch [2048x2048] = Q * K^T / 32, lower-triangle blocks only
  gemm_bt<2><<<dim3(16, 16, 4), 256, 0, stream>>>(Q, Kb, Sc, nullptr, 1024,
      (long)2048 * 1024, (long)2048 * 1024, (long)2048 * 2048, 0.03125f);

  softmax_rows<<<dim3(2048, 4), 256, 0, stream>>>(Sc, P);

  // out: per batch [2048x1024] = P * Vt^T, K clamped per block-row
  gemm_bt<3><<<dim3(8, 16, 4), 256, 0, stream>>>(P, Vt, out, nullptr, 2048,
      (long)2048 * 2048, (long)1024 * 2048, (long)2048 * 1024, 1.f);
}

// Round 3
// 259.123 us; speedup vs baseline: 1.3231x; 1.1506x over previous
//
#include <hip/hip_runtime.h>

typedef __attribute__((ext_vector_type(8))) short bf16x8;
typedef __attribute__((ext_vector_type(4))) float f32x4;
typedef unsigned int u32;

__device__ __forceinline__ unsigned short f2bf(float f) {
  union { float f; unsigned int u; } a; a.f = f;
  unsigned int u = a.u;
  u += 0x7FFFu + ((u >> 16) & 1u);   // RNE
  return (unsigned short)(u >> 16);
}

// async global->LDS, 16B per lane. LDS dest = wave-uniform base + lane*16.
__device__ __forceinline__ void gload16(const unsigned short* g, unsigned short* l) {
  __builtin_amdgcn_global_load_lds((const __attribute__((address_space(1))) u32*)g,
                                   (__attribute__((address_space(3))) u32*)l, 16, 0, 0);
}

#define TM 128
#define TN 128
#define BK 64
// LDS tile: [128 rows][64 elems] = 128B/row (rows alias all 32 banks exactly).
// XOR chunk swizzle: physical 16B chunk p of row r holds logical chunk p ^ (r&7).
// DMA write side: global col = ((lane&7) ^ (lane>>3))*8, invariant across the 4
// 8-row groups (+8*K per group). Fragment read: phys = (quad+4h) ^ (l16&7) --
// conflict-free under the 8-consecutive-lane phase model (R2 measured 0 conflicts).

// C = A[M][K] * B[N][K]^T, bf16 in, fp32 accum.
// MODE 0: fused QKV. B = Wcat[3072][1024]; n-range 0->Q bf16, 1->K bf16, 2->Vt transposed
// MODE 2: scores: fp32 C*scale, stride 2048, skip blocks above diagonal
// MODE 3: PV: fp32 C, stride 1024, K clamped to bm+TM
template<int MODE>
__global__ __launch_bounds__(256)
void gemm_bt(const unsigned short* __restrict__ A,
             const unsigned short* __restrict__ Bm,
             float* __restrict__ Cf,
             unsigned short* __restrict__ Cb,
             int K, long aBatch, long bBatch, long cBatch, float scale)
{
  int z = blockIdx.z;
  A  += (long)z * aBatch;
  Bm += (long)z * bBatch;
  if (MODE == 2 || MODE == 3) Cf += (long)z * cBatch;

  int bm = blockIdx.y * TM;
  int bn = blockIdx.x * TN;
  if (MODE == 2 && bn > bm + (TM - 1)) return;   // fully above causal diagonal
  int Keff = K;
  if (MODE == 3) Keff = min(K, bm + TM);

  __shared__ __align__(16) unsigned short As[TM * BK];
  __shared__ __align__(16) unsigned short Bs[TN * BK];

  int tid  = threadIdx.x;
  int wave = tid >> 6, lane = tid & 63;
  int wm = (wave >> 1) * 64, wn = (wave & 1) * 64;
  int quad = lane >> 4, l16 = lane & 15;

  // ---- staging: wave stages rows [wave*32, wave*32+32), 4 instrs of 8 rows each
  int r8 = lane >> 3;                  // 0..7 within 8-row group
  int c  = (lane & 7) ^ r8;            // swizzled logical chunk for this lane
  int rs = wave * 32 + r8;
  const unsigned short* Ag = A  + (long)(bm + rs) * K + c * 8;
  const unsigned short* Bg = Bm + (long)(bn + rs) * K + c * 8;
  unsigned short* Al = &As[(wave * 32) * BK];
  unsigned short* Bl = &Bs[(wave * 32) * BK];

  f32x4 acc[4][4] = {};

  for (int k0 = 0; k0 < Keff; k0 += BK) {
#pragma unroll
    for (int g = 0; g < 4; g++) {
      gload16(Ag + k0 + (long)g * 8 * K, Al + g * 8 * BK);
      gload16(Bg + k0 + (long)g * 8 * K, Bl + g * 8 * BK);
    }
    __syncthreads();

#pragma unroll
    for (int h = 0; h < 2; h++) {
      bf16x8 af[4], bfr[4];
#pragma unroll
      for (int i = 0; i < 4; i++)
        af[i]  = *(const bf16x8*)&As[(wm + i * 16 + l16) * BK + (((quad + 4 * h) ^ (l16 & 7)) * 8)];
#pragma unroll
      for (int j = 0; j < 4; j++)
        bfr[j] = *(const bf16x8*)&Bs[(wn + j * 16 + l16) * BK + (((quad + 4 * h) ^ (l16 & 7)) * 8)];
#pragma unroll
      for (int i = 0; i < 4; i++)
#pragma unroll
        for (int j = 0; j < 4; j++)
          acc[i][j] = __builtin_amdgcn_mfma_f32_16x16x32_bf16(af[i], bfr[j], acc[i][j], 0, 0, 0);
    }
    __syncthreads();
  }

  // Epilogue. C/D layout: col = lane&15, row = quad*4 + reg  [m89/m91]
#pragma unroll
  for (int i = 0; i < 4; i++) {
    int grow0 = bm + wm + i * 16 + quad * 4;
#pragma unroll
    for (int j = 0; j < 4; j++) {
      int gcol = bn + wn + j * 16 + l16;
      if (MODE == 0) {
        int which = gcol >> 10;       // block-uniform (bn multiple of 128)
        int col = gcol & 1023;
        if (which < 2) {
          unsigned short* dst = Cb + (long)which * 8192 * 1024;   // Q or K
#pragma unroll
          for (int r = 0; r < 4; r++)
            dst[(long)(grow0 + r) * 1024 + col] = f2bf(acc[i][j][r]);
        } else {                       // Vt[b][col][s], 4-row pack along s
          unsigned short* Vt = Cb + (long)2 * 8192 * 1024;
          int bb = grow0 >> 11, s = grow0 & 2047;
          ushort4 pk;
          pk.x = f2bf(acc[i][j][0]); pk.y = f2bf(acc[i][j][1]);
          pk.z = f2bf(acc[i][j][2]); pk.w = f2bf(acc[i][j][3]);
          *(ushort4*)(Vt + ((long)bb * 1024 + col) * 2048 + s) = pk;
        }
      } else if (MODE == 2) {
#pragma unroll
        for (int r = 0; r < 4; r++)
          Cf[(long)(grow0 + r) * 2048 + gcol] = acc[i][j][r] * scale;
      } else {
#pragma unroll
        for (int r = 0; r < 4; r++)
          Cf[(long)(grow0 + r) * 1024 + gcol] = acc[i][j][r];
      }
    }
  }
}

__global__ __launch_bounds__(256)
void cvt_bf16(const float* __restrict__ in, unsigned short* __restrict__ out, long n)
{
  long i = ((long)blockIdx.x * 256 + threadIdx.x) * 4;
  if (i >= n) return;
  float4 v = *(const float4*)(in + i);
  ushort4 o;
  o.x = f2bf(v.x); o.y = f2bf(v.y); o.z = f2bf(v.z); o.w = f2bf(v.w);
  *(ushort4*)(out + i) = o;
}

// W[k][n] fp32 -> WT[n][k] bf16 (1024x1024), 3 matrices via blockIdx.z
__global__ __launch_bounds__(256)
void trans_cvt(const float* __restrict__ W0, const float* __restrict__ W1, const float* __restrict__ W2,
               unsigned short* __restrict__ T0, unsigned short* __restrict__ T1, unsigned short* __restrict__ T2)
{
  int z = blockIdx.z;
  const float* W   = (z == 0) ? W0 : (z == 1) ? W1 : W2;
  unsigned short* T = (z == 0) ? T0 : (z == 1) ? T1 : T2;
  __shared__ float tile[32][33];
  int kb = blockIdx.x * 32, nb = blockIdx.y * 32;
  int tx = threadIdx.x & 31, ty = threadIdx.x >> 5;
  for (int r = ty; r < 32; r += 8)
    tile[r][tx] = W[(long)(kb + r) * 1024 + nb + tx];
  __syncthreads();
  for (int r = ty; r < 32; r += 8)
    T[(long)(nb + r) * 1024 + kb + tx] = f2bf(tile[tx][r]);
}

// one 256-thread block per row; reads S[row][0..row], writes P bf16 (zeros above diag)
__global__ __launch_bounds__(256)
void softmax_rows(const float* __restrict__ Sc, unsigned short* __restrict__ P)
{
  int row = blockIdx.x, b = blockIdx.y;
  const float* Sr = Sc + ((long)b * 2048 + row) * 2048;
  unsigned short* Pr = P + ((long)b * 2048 + row) * 2048;
  int n = row + 1;
  int tid = threadIdx.x;
  int wave = tid >> 6, lane = tid & 63;
  __shared__ float sh[2048];
  __shared__ float red[4];

  float lmax = -1e30f;
  for (int j0 = tid * 4; j0 < n; j0 += 1024) {
    float4 v = *(const float4*)(Sr + j0);
    v.x = (j0 + 0 < n) ? v.x : -1e30f;
    v.y = (j0 + 1 < n) ? v.y : -1e30f;
    v.z = (j0 + 2 < n) ? v.z : -1e30f;
    v.w = (j0 + 3 < n) ? v.w : -1e30f;
    *(float4*)(sh + j0) = v;
    lmax = fmaxf(fmaxf(v.x, v.y), fmaxf(fmaxf(v.z, v.w), lmax));
  }
  for (int off = 32; off; off >>= 1) lmax = fmaxf(lmax, __shfl_down(lmax, off));
  if (lane == 0) red[wave] = lmax;
  __syncthreads();
  float rmax = fmaxf(fmaxf(red[0], red[1]), fmaxf(red[2], red[3]));
  __syncthreads();

  float lsum = 0.f;
  for (int j0 = tid * 4; j0 < n; j0 += 1024) {
    float4 v = *(const float4*)(sh + j0);
    v.x = __expf(v.x - rmax); v.y = __expf(v.y - rmax);
    v.z = __expf(v.z - rmax); v.w = __expf(v.w - rmax);
    *(float4*)(sh + j0) = v;
    lsum += v.x + v.y + v.z + v.w;
  }
  for (int off = 32; off; off >>= 1) lsum += __shfl_down(lsum, off);
  if (lane == 0) red[wave] = lsum;
  __syncthreads();
  float rinv = 1.0f / (red[0] + red[1] + red[2] + red[3]);

  for (int j0 = tid * 4; j0 < 2048; j0 += 1024) {
    ushort4 o;
    if (j0 < n) {
      float4 v = *(const float4*)(sh + j0);
      o.x = f2bf(v.x * rinv); o.y = f2bf(v.y * rinv);
      o.z = f2bf(v.z * rinv); o.w = f2bf(v.w * rinv);
    } else {
      o.x = o.y = o.z = o.w = 0;
    }
    *(ushort4*)(Pr + j0) = o;
  }
}

extern "C" void kernel_launch(void* const* d_in, const int* in_sizes, int n_in,
                              void* d_out, int out_size, void* d_ws, size_t ws_size,
                              hipStream_t stream) {
  const float* x  = (const float*)d_in[0];
  const float* Wq = (const float*)d_in[1];
  const float* Wk = (const float*)d_in[2];
  const float* Wv = (const float*)d_in[3];
  float* out = (float*)d_out;

  // workspace layout (bf16 = unsigned short), ~166 MB total
  unsigned short* Xb  = (unsigned short*)d_ws;            // [8192][1024]
  unsigned short* WqT = Xb  + (long)8192 * 1024;          // [3072][1024] contiguous (q,k,v)
  unsigned short* WkT = WqT + (long)1024 * 1024;
  unsigned short* WvT = WkT + (long)1024 * 1024;
  unsigned short* Q   = WvT + (long)1024 * 1024;          // [8192][1024]
  unsigned short* Kb  = Q   + (long)8192 * 1024;          // [8192][1024]
  unsigned short* Vt  = Kb  + (long)8192 * 1024;          // [4][1024][2048]
  float* Sc           = (float*)(Vt + (long)8192 * 1024); // [4][2048][2048] fp32
  unsigned short* P   = (unsigned short*)(Sc + (long)4 * 2048 * 2048); // [4][2048][2048]

  cvt_bf16<<<8192, 256, 0, stream>>>(x, Xb, (long)8388608);
  trans_cvt<<<dim3(32, 32, 3), 256, 0, stream>>>(Wq, Wk, Wv, WqT, WkT, WvT);

  // fused QKV: [8192x3072] = Xb * Wcat^T, epilogue splits into Q, K, Vt
  gemm_bt<0><<<dim3(24, 64, 1), 256, 0, stream>>>(Xb, WqT, nullptr, Q, 1024, 0, 0, 0, 1.f);

  // scores: per batch [2048x2048] = Q * K^T / 32, lower-triangle blocks only
  gemm_bt<2><<<dim3(16, 16, 4), 256, 0, stream>>>(Q, Kb, Sc, nullptr, 1024,
      (long)2048 * 1024, (long)2048 * 1024, (long)2048 * 2048, 0.03125f);

  softmax_rows<<<dim3(2048, 4), 256, 0, stream>>>(Sc, P);

  // out: per batch [2048x1024] = P * Vt^T, K clamped per block-row
  gemm_bt<3><<<dim3(8, 16, 4), 256, 0, stream>>>(P, Vt, out, nullptr, 2048,
      (long)2048 * 2048, (long)1024 * 2048, (long)2048 * 1024, 1.f);
}